// Round 6
// baseline (1127.025 us; speedup 1.0000x reference)
//
#include <hip/hip_runtime.h>
#include <hip/hip_bf16.h>
#include <cstdint>
#include <cstddef>

// Problem constants
#define B_   2
#define T_   2048
#define DIM_ 4096
#define H_   32
#define HKV_ 8
#define DH_  128
#define MROWS (B_*T_)    // 4096
#define QKV_LD 6144      // fused QKV row stride (4096 Q + 1024 K + 1024 V)

typedef __bf16 bf16_t;
typedef bf16_t bf16x8 __attribute__((ext_vector_type(8)));
typedef bf16_t bf16x4 __attribute__((ext_vector_type(4)));
typedef float  f32x4  __attribute__((ext_vector_type(4)));

typedef __attribute__((address_space(1))) void gvoid_t;
typedef __attribute__((address_space(3))) void lvoid_t;

__device__ __forceinline__ void gld_lds16(const void* g, void* l) {
  __builtin_amdgcn_global_load_lds((gvoid_t*)g, (lvoid_t*)l, 16, 0, 0);
}

__device__ __forceinline__ f32x4 mfma16(bf16x8 a, bf16x8 b, f32x4 c) {
  return __builtin_amdgcn_mfma_f32_16x16x32_bf16(a, b, c, 0, 0, 0);
}

// ---------------------------------------------------------------------------
// 1) elementwise cast fp32 -> bf16 (X)
// ---------------------------------------------------------------------------
__global__ void cast_f32_bf16(const float* __restrict__ in,
                              bf16_t* __restrict__ out, int n4) {
  int i = blockIdx.x * blockDim.x + threadIdx.x;
  if (i < n4) {
    float4 v = ((const float4*)in)[i];
    bf16x4 o;
    o[0] = (bf16_t)v.x; o[1] = (bf16_t)v.y; o[2] = (bf16_t)v.z; o[3] = (bf16_t)v.w;
    ((bf16x4*)out)[i] = o;
  }
}

// ---------------------------------------------------------------------------
// 2) transpose + cast: in fp32 [K][N] -> out bf16 [N][K]
// ---------------------------------------------------------------------------
__global__ void transpose_cast(const float* __restrict__ in,
                               bf16_t* __restrict__ out, int K, int N) {
  __shared__ float tile[32][33];
  int n0 = blockIdx.x * 32, k0 = blockIdx.y * 32;
  int tx = threadIdx.x, ty = threadIdx.y;
#pragma unroll
  for (int j = 0; j < 4; ++j)
    tile[ty + j*8][tx] = in[(size_t)(k0 + ty + j*8) * N + n0 + tx];
  __syncthreads();
#pragma unroll
  for (int j = 0; j < 4; ++j)
    out[(size_t)(n0 + ty + j*8) * K + k0 + tx] = (bf16_t)tile[tx][ty + j*8];
}

// ---------------------------------------------------------------------------
// 3) bf16 MFMA GEMM, m97 structure: C[M][N] = A[M][K] * BT[N][K]^T
// ---------------------------------------------------------------------------
template <int OUT_F32>
__global__ __launch_bounds__(256, 2)
void gemm_bt(const bf16_t* __restrict__ A, const bf16_t* __restrict__ BT,
             void* __restrict__ C, int M, int N, int K) {
  __shared__ __align__(16) bf16_t Als[128 * 32];
  __shared__ __align__(16) bf16_t Bls[128 * 32];
  const int tid  = threadIdx.x;
  const int wave = tid >> 6, lane = tid & 63;
  const int quad = lane >> 4, l16 = lane & 15;
  const int wm = wave >> 1, wn = wave & 1;
  const int m0 = blockIdx.y * 128, n0 = blockIdx.x * 128;

  f32x4 acc[4][4] = {};

  const int srow = lane >> 2;
  const int scol = (lane & 3) * 8;

  for (int k0 = 0; k0 < K; k0 += 32) {
#pragma unroll
    for (int c = 0; c < 2; ++c) {
      int ch = wave * 2 + c;
      gld_lds16(A + (size_t)(m0 + ch*16 + srow) * K + k0 + scol,
                &Als[ch*512 + srow*32 + scol]);
    }
#pragma unroll
    for (int c = 0; c < 2; ++c) {
      int ch = wave * 2 + c;
      gld_lds16(BT + (size_t)(n0 + ch*16 + srow) * K + k0 + scol,
                &Bls[ch*512 + srow*32 + scol]);
    }
    __syncthreads();

    bf16x8 af[4], bfr[4];
#pragma unroll
    for (int mi = 0; mi < 4; ++mi)
      af[mi] = *(const bf16x8*)&Als[(wm*64 + mi*16 + l16)*32 + quad*8];
#pragma unroll
    for (int ni = 0; ni < 4; ++ni)
      bfr[ni] = *(const bf16x8*)&Bls[(wn*64 + ni*16 + l16)*32 + quad*8];
#pragma unroll
    for (int mi = 0; mi < 4; ++mi)
#pragma unroll
      for (int ni = 0; ni < 4; ++ni)
        acc[mi][ni] = mfma16(af[mi], bfr[ni], acc[mi][ni]);
    __syncthreads();
  }

#pragma unroll
  for (int mi = 0; mi < 4; ++mi)
#pragma unroll
    for (int ni = 0; ni < 4; ++ni)
#pragma unroll
      for (int r = 0; r < 4; ++r) {
        int row = m0 + wm*64 + mi*16 + quad*4 + r;
        int col = n0 + wn*64 + ni*16 + l16;
        if (OUT_F32)
          ((float*)C)[(size_t)row * N + col] = acc[mi][ni][r];
        else
          ((bf16_t*)C)[(size_t)row * N + col] = (bf16_t)acc[mi][ni][r];
      }
}

// ---------------------------------------------------------------------------
// 4) in-place RoPE on bf16 rows of stride ld; head layout [Hn][128] at col h*128
// ---------------------------------------------------------------------------
__global__ void rope_kernel(bf16_t* __restrict__ X, int Hn, int ld, int total) {
  int i = blockIdx.x * blockDim.x + threadIdx.x;
  if (i >= total) return;
  int d   = i & 63;
  int rem = i >> 6;
  int h   = rem % Hn; rem /= Hn;
  int t   = rem % T_;
  int b   = rem / T_;
  size_t base = (size_t)(b * T_ + t) * ld + h * DH_;
  float x1 = (float)X[base + d];
  float x2 = (float)X[base + 64 + d];
  float inv_freq = expf(-(float)d * 0.14391156758f);
  float ang = (float)t * inv_freq;
  float s, c;
  sincosf(ang, &s, &c);
  X[base + d]      = (bf16_t)(x1 * c - x2 * s);
  X[base + 64 + d] = (bf16_t)(x1 * s + x2 * c);
}

// ---------------------------------------------------------------------------
// 5) V transpose: V rows (stride ld) [b][t][kv*128+d] -> VT [b][kv][128][T]
// ---------------------------------------------------------------------------
__global__ void v_transpose(const bf16_t* __restrict__ Vb,
                            bf16_t* __restrict__ VT, int ld) {
  __shared__ bf16_t tile[32][33];
  int t0 = blockIdx.x * 32;
  int d0 = blockIdx.y * 32;
  int bk = blockIdx.z;
  int b = bk >> 3, kv = bk & 7;
  int tx = threadIdx.x, ty = threadIdx.y;
#pragma unroll
  for (int j = 0; j < 4; ++j)
    tile[ty + j*8][tx] =
        Vb[(size_t)(b * T_ + t0 + ty + j*8) * ld + kv*DH_ + d0 + tx];
  __syncthreads();
#pragma unroll
  for (int j = 0; j < 4; ++j)
    VT[((size_t)bk * DH_ + d0 + ty + j*8) * T_ + t0 + tx] = tile[tx][ty + j*8];
}

// ---------------------------------------------------------------------------
// 6) causal flash attention. BQ=64 (16 rows/wave), BKV=64, 256 threads.
//    Theory (r4 post-mortem, untested due to r5 infra failure): occupancy
//    21.6% across three schedules is a RESIDENCY CAP (2 blocks/CU) from the
//    real per-wave register footprint (~200, unified arch+acc file on
//    gfx950). Halving per-wave state (o_acc 64->32, s 32->16, q 32->16)
//    plus __launch_bounds__(256,4) (targets <=128 VGPR) should give
//    4 waves/SIMD -> 4 blocks/CU.
//    Grid = 2048 blocks (32 qb x 64 bh), qb descending (LPT), kv = id&7
//    (XCD L2 affinity). Direct output; no split-KV.
//    Softmax: vote-only max, l-via-MFMA, exp2 domain, defer-max (verified).
// ---------------------------------------------------------------------------
__global__ __launch_bounds__(256, 4)
void flash_attn(const bf16_t* __restrict__ QKV, const bf16_t* __restrict__ VT,
                bf16_t* __restrict__ Ob) {
  __shared__ __align__(16) bf16_t Pls[64 * 72];   // [q][kv], +8 pad

  const int tid = threadIdx.x, wave = tid >> 6, lane = tid & 63;
  const int quad = lane >> 4, l16 = lane & 15;

  // decode: id = item*64 + w ; item 0..31 -> qb = 31-item (heavy first);
  // w -> kv = w&7 (XCD affinity), b, head-sub
  const int id = blockIdx.x;
  const int w  = id & 63;
  const int qb = 31 - (id >> 6);
  const int kv = w & 7, b = (w >> 3) & 1;
  const int h  = kv * 4 + (w >> 4);

  // Q fragments (rope already applied): wave's 16 rows, row = l16
  bf16x8 q[4];
  {
    const bf16_t* base =
        QKV + (size_t)(b*T_ + qb*64 + wave*16 + l16) * QKV_LD + h*DH_;
#pragma unroll
    for (int kk = 0; kk < 4; ++kk)
      q[kk] = *(const bf16x8*)(base + kk*32 + quad*8);
  }

  float m_st[4];
  f32x4 o_acc[8] = {};
  f32x4 l_acc = {};
#pragma unroll
  for (int r = 0; r < 4; ++r) m_st[r] = -1e30f;

  const int nkv = qb + 1;
  const float S2 = 0.08838834764831845f * 1.4426950408889634f; // sc*log2(e)
  const float THRraw = 8.0f / 0.08838834764831845f;            // defer threshold

  const bf16_t* Kbase = QKV + DIM_ + (size_t)b * T_ * QKV_LD + kv * DH_;
  const bf16_t* Vbase = VT + (size_t)(b*HKV_ + kv) * DH_ * T_;

  bf16x8 vones;
#pragma unroll
  for (int i = 0; i < 8; ++i) vones[i] = (bf16_t)1.0f;

  for (int kvt = 0; kvt < nkv; ++kvt) {
    // ---- S = Q K^T : K fragments straight from global (L2/L3-hot) ----
    f32x4 s[4] = {};
#pragma unroll
    for (int kk = 0; kk < 4; ++kk) {
      bf16x8 kf[4];
#pragma unroll
      for (int ni = 0; ni < 4; ++ni) {
        int krow = kvt*64 + ni*16 + l16;
        kf[ni] = *(const bf16x8*)(Kbase + (size_t)krow * QKV_LD + kk*32 + quad*8);
      }
      __builtin_amdgcn_s_setprio(1);
#pragma unroll
      for (int ni = 0; ni < 4; ++ni)
        s[ni] = mfma16(q[kk], kf[ni], s[ni]);
      __builtin_amdgcn_s_setprio(0);
    }

    // ---- causal mask + online softmax (vote-only max; l via MFMA) ----
    const bool need_mask = (kvt == qb);
    float lmax[4];
#pragma unroll
    for (int r = 0; r < 4; ++r) {
      int rpos = qb*64 + wave*16 + quad*4 + r;
      float m = -1e30f;
#pragma unroll
      for (int ni = 0; ni < 4; ++ni) {
        float v = s[ni][r];
        if (need_mask) {
          int cpos = kvt*64 + ni*16 + l16;
          if (cpos > rpos) v = -1e30f;
        }
        s[ni][r] = v;
        m = fmaxf(m, v);
      }
      lmax[r] = m;
    }
    bool defer = (lmax[0] <= m_st[0] + THRraw) &
                 (lmax[1] <= m_st[1] + THRraw) &
                 (lmax[2] <= m_st[2] + THRraw) &
                 (lmax[3] <= m_st[3] + THRraw);
    if (!__all(defer)) {
      float al[4];
#pragma unroll
      for (int r = 0; r < 4; ++r) {
        float m = lmax[r];
#pragma unroll
        for (int off = 1; off < 16; off <<= 1)
          m = fmaxf(m, __shfl_xor(m, off, 64));
        float mnew = fmaxf(m_st[r], m);
        al[r] = __builtin_amdgcn_exp2f((m_st[r] - mnew) * S2);
        m_st[r] = mnew;
      }
#pragma unroll
      for (int ni = 0; ni < 8; ++ni)
#pragma unroll
        for (int r = 0; r < 4; ++r) o_acc[ni][r] *= al[r];
#pragma unroll
      for (int r = 0; r < 4; ++r) l_acc[r] *= al[r];
    }
    // exp2 + P write (common path; wave-private rows, no barrier)
#pragma unroll
    for (int r = 0; r < 4; ++r) {
      float mn2 = m_st[r] * S2;
      int prow = wave*16 + quad*4 + r;
#pragma unroll
      for (int ni = 0; ni < 4; ++ni) {
        float pv = __builtin_amdgcn_exp2f(fmaf(s[ni][r], S2, -mn2));
        Pls[prow*72 + ni*16 + l16] = (bf16_t)pv;
      }
    }

    // ---- O += P V ; l += P 1 (MFMA rowsum) ----
    bf16x8 pf[2];
#pragma unroll
    for (int kk = 0; kk < 2; ++kk)
      pf[kk] = *(const bf16x8*)&Pls[(wave*16 + l16)*72 + kk*32 + quad*8];

    __builtin_amdgcn_s_setprio(1);
    l_acc = mfma16(pf[0], vones, l_acc);
    l_acc = mfma16(pf[1], vones, l_acc);
    __builtin_amdgcn_s_setprio(0);

#pragma unroll
    for (int ni = 0; ni < 8; ++ni) {
      int drow = ni*16 + l16;
      const bf16_t* vb = Vbase + (size_t)drow * T_ + kvt*64;
      bf16x8 va = *(const bf16x8*)(vb + quad*8);
      bf16x8 vc = *(const bf16x8*)(vb + 32 + quad*8);
      __builtin_amdgcn_s_setprio(1);
      o_acc[ni] = mfma16(pf[0], va, o_acc[ni]);
      o_acc[ni] = mfma16(pf[1], vc, o_acc[ni]);
      __builtin_amdgcn_s_setprio(0);
    }
  }

  // epilogue: normalize (l from MFMA rowsum) and store bf16
  {
    float inv[4];
#pragma unroll
    for (int r = 0; r < 4; ++r) inv[r] = 1.f / l_acc[r];
#pragma unroll
    for (int ni = 0; ni < 8; ++ni)
#pragma unroll
      for (int r = 0; r < 4; ++r) {
        size_t row = (size_t)(b*T_ + qb*64 + wave*16 + quad*4 + r);
        int col = h*DH_ + ni*16 + l16;
        Ob[row * DIM_ + col] = (bf16_t)(o_acc[ni][r] * inv[r]);
      }
  }
}

// ---------------------------------------------------------------------------
// launch
// ---------------------------------------------------------------------------
extern "C" void kernel_launch(void* const* d_in, const int* in_sizes, int n_in,
                              void* d_out, int out_size, void* d_ws, size_t ws_size,
                              hipStream_t stream) {
  const float* X  = (const float*)d_in[0];
  const float* Wq = (const float*)d_in[1];
  const float* Wk = (const float*)d_in[2];
  const float* Wv = (const float*)d_in[3];
  const float* Wo = (const float*)d_in[4];
  float* out = (float*)d_out;

  // workspace layout (bytes); total ~176.2 MB
  char* ws = (char*)d_ws;
  const size_t SZ_X   = (size_t)MROWS * DIM_ * 2;     // 33.55 MB
  const size_t SZ_WQ  = (size_t)DIM_ * DIM_ * 2;      // 33.55 MB
  const size_t SZ_WK  = (size_t)DIM_ * 1024 * 2;      // 8.39 MB
  const size_t SZ_QKV = (size_t)MROWS * QKV_LD * 2;   // 50.33 MB
  bf16_t* Xb  = (bf16_t*)(ws);                        // X bf16; reused as Ob
  bf16_t* WqT = (bf16_t*)(ws + SZ_X);                 // [4096][4096]
  bf16_t* WkT = (bf16_t*)(ws + SZ_X + SZ_WQ);         // [1024][4096]
  bf16_t* WvT = (bf16_t*)(ws + SZ_X + SZ_WQ + SZ_WK); // [1024][4096]
  bf16_t* WoT = (bf16_t*)(ws + SZ_X + SZ_WQ + 2*SZ_WK);
  bf16_t* QKV = (bf16_t*)(ws + SZ_X + 2*SZ_WQ + 2*SZ_WK);  // [4096][6144]
  bf16_t* VT  = (bf16_t*)(ws + SZ_X + 2*SZ_WQ + 2*SZ_WK + SZ_QKV);
  bf16_t* Ob  = Xb;  // X dead after QKV GEMM

  // 1) casts / transposes
  {
    int n4 = MROWS * DIM_ / 4;
    cast_f32_bf16<<<(n4 + 255)/256, 256, 0, stream>>>(X, Xb, n4);
  }
  transpose_cast<<<dim3(DIM_/32, DIM_/32), dim3(32,8), 0, stream>>>(Wq, WqT, DIM_, DIM_);
  transpose_cast<<<dim3(1024/32, DIM_/32), dim3(32,8), 0, stream>>>(Wk, WkT, DIM_, 1024);
  transpose_cast<<<dim3(1024/32, DIM_/32), dim3(32,8), 0, stream>>>(Wv, WvT, DIM_, 1024);
  transpose_cast<<<dim3(DIM_/32, DIM_/32), dim3(32,8), 0, stream>>>(Wo, WoT, DIM_, DIM_);

  // 2) fused QKV projection: C[4096][6144] = Xb * [Wq|Wk|Wv]
  gemm_bt<0><<<dim3(QKV_LD/128, MROWS/128), 256, 0, stream>>>(Xb, WqT, QKV, MROWS, QKV_LD, DIM_);

  // 3) RoPE (in place, inside fused buffer)
  {
    int totq = B_ * T_ * H_ * 64;
    rope_kernel<<<(totq + 255)/256, 256, 0, stream>>>(QKV, H_, QKV_LD, totq);
    int totk = B_ * T_ * HKV_ * 64;
    rope_kernel<<<(totk + 255)/256, 256, 0, stream>>>(QKV + DIM_, HKV_, QKV_LD, totk);
  }

  // 4) V transpose (V columns live at QKV + 5120)
  v_transpose<<<dim3(T_/32, DH_/32, B_*HKV_), dim3(32,8), 0, stream>>>(QKV + DIM_ + 1024, VT, QKV_LD);

  // 5) flash attention: 2048 blocks (32 qb x 64 bh), LPT + XCD decode inside
  flash_attn<<<dim3(32 * 64), 256, 0, stream>>>(QKV, VT, Ob);

  // 6) output projection -> fp32 d_out
  gemm_bt<1><<<dim3(DIM_/128, MROWS/128), 256, 0, stream>>>(Ob, WoT, out, MROWS, DIM_, DIM_);
}